// Round 1
// baseline (466.486 us; speedup 1.0000x reference)
//
#include <hip/hip_runtime.h>
#include <cstddef>

#define B_ 2
#define NQ_ 10000
#define C_ 256
#define M_ 8
#define L_ 3
#define K_ 4
#define D_ 32
#define P_ 13125   // 10000 + 2500 + 625

// ---------------------------------------------------------------------------
// Tiled fp32 GEMM:  Cout[rows, Ntot] = A[rows, 256] @ Bcat[Ntot, 256]^T + bias
// Bcat = concat(B1[N1], B2[Ntot-N1]) by rows. Tile 64x64, BK=64, 256 thr,
// 4x4 microtile. LDS is K-major (As[k][p]) so fragment reads are b128.
// ---------------------------------------------------------------------------
__global__ __launch_bounds__(256) void gemm_rowA(
    const float* __restrict__ A, int rows,
    const float* __restrict__ B1, const float* __restrict__ bias1, int N1,
    const float* __restrict__ B2, const float* __restrict__ bias2, int Ntot,
    float* __restrict__ Cout)
{
    __shared__ float As[64][68];
    __shared__ float Bs[64][68];
    const int t   = threadIdx.x;
    const int row0 = blockIdx.x * 64;
    const int o0   = blockIdx.y * 64;
    const int tp = (t & 15) * 4;   // row within tile
    const int to = (t >> 4) * 4;   // col within tile

    float acc[4][4] = {};

    for (int kt = 0; kt < 256; kt += 64) {
        // A tile: float4 loads (coalesced along k), scatter to K-major LDS
        #pragma unroll
        for (int i = 0; i < 4; ++i) {
            int idx = i * 256 + t;        // float4 slot 0..1023
            int p   = idx >> 4;           // 0..63 row
            int c4  = (idx & 15) * 4;     // 0..60 k
            float4 v = make_float4(0.f, 0.f, 0.f, 0.f);
            int row = row0 + p;
            if (row < rows)
                v = *reinterpret_cast<const float4*>(A + (size_t)row * 256 + kt + c4);
            As[c4 + 0][p] = v.x; As[c4 + 1][p] = v.y;
            As[c4 + 2][p] = v.z; As[c4 + 3][p] = v.w;
        }
        // B tile
        #pragma unroll
        for (int i = 0; i < 4; ++i) {
            int idx = i * 256 + t;
            int o   = idx >> 4;
            int c4  = (idx & 15) * 4;
            float4 v = make_float4(0.f, 0.f, 0.f, 0.f);
            int oo = o0 + o;
            if (oo < Ntot) {
                const float* Bm = (oo < N1) ? (B1 + (size_t)oo * 256)
                                            : (B2 + (size_t)(oo - N1) * 256);
                v = *reinterpret_cast<const float4*>(Bm + kt + c4);
            }
            Bs[c4 + 0][o] = v.x; Bs[c4 + 1][o] = v.y;
            Bs[c4 + 2][o] = v.z; Bs[c4 + 3][o] = v.w;
        }
        __syncthreads();

        #pragma unroll 8
        for (int kk = 0; kk < 64; ++kk) {
            const float4 a4 = *reinterpret_cast<const float4*>(&As[kk][tp]);
            const float4 b4 = *reinterpret_cast<const float4*>(&Bs[kk][to]);
            const float av[4] = {a4.x, a4.y, a4.z, a4.w};
            const float bw[4] = {b4.x, b4.y, b4.z, b4.w};
            #pragma unroll
            for (int i = 0; i < 4; ++i)
                #pragma unroll
                for (int j = 0; j < 4; ++j)
                    acc[i][j] = fmaf(av[i], bw[j], acc[i][j]);
        }
        __syncthreads();
    }

    // Store with bias (o multiples of 4; N1 and Ntot are multiples of 4)
    const int oc = o0 + to;
    if (oc < Ntot) {
        const float* bptr = (oc < N1) ? (bias1 + oc) : (bias2 + (oc - N1));
        #pragma unroll
        for (int i = 0; i < 4; ++i) {
            int row = row0 + tp + i;
            if (row >= rows) continue;
            float4 r;
            r.x = acc[i][0] + bptr[0];
            r.y = acc[i][1] + bptr[1];
            r.z = acc[i][2] + bptr[2];
            r.w = acc[i][3] + bptr[3];
            *reinterpret_cast<float4*>(Cout + (size_t)row * Ntot + oc) = r;
        }
    }
}

// ---------------------------------------------------------------------------
// Value projection (1x1 conv as GEMM):
//   proj[b, lvl_off + p, o] = sum_c Wv[o,c] * value_lvl[b,c,p] + bv[o]
// A is column-strided (A[p,c] = V[c*HW + p]) -> scalar coalesced loads,
// conflict-free K-major LDS writes.
// ---------------------------------------------------------------------------
__global__ __launch_bounds__(256) void proj_kernel(
    const float* __restrict__ v0, const float* __restrict__ v1,
    const float* __restrict__ v2,
    const float* __restrict__ Wv, const float* __restrict__ bv,
    float* __restrict__ proj)
{
    constexpr int HWs[3]  = {10000, 2500, 625};
    constexpr int offs[3] = {0, 10000, 12500};

    const int z   = blockIdx.z;       // b*3 + lvl
    const int b   = z / 3;
    const int lvl = z % 3;
    const int HW  = HWs[lvl];
    const int p0  = blockIdx.x * 64;
    if (p0 >= HW) return;
    const int o0 = blockIdx.y * 64;

    const float* V = (lvl == 0 ? v0 : (lvl == 1 ? v1 : v2)) + (size_t)b * 256 * HW;

    __shared__ float As[64][68];
    __shared__ float Bs[64][68];
    const int t  = threadIdx.x;
    const int tp = (t & 15) * 4;
    const int to = (t >> 4) * 4;

    float acc[4][4] = {};

    for (int kt = 0; kt < 256; kt += 64) {
        // A tile: As[c][p] = V[(kt+c)*HW + p0+p]; coalesced over p
        #pragma unroll
        for (int i = 0; i < 16; ++i) {
            int idx = i * 256 + t;
            int p   = idx & 63;
            int c   = idx >> 6;
            float v = 0.f;
            if (p0 + p < HW)
                v = V[(size_t)(kt + c) * HW + p0 + p];
            As[c][p] = v;
        }
        // B tile from Wv (row-major)
        #pragma unroll
        for (int i = 0; i < 4; ++i) {
            int idx = i * 256 + t;
            int o   = idx >> 4;
            int c4  = (idx & 15) * 4;
            float4 v = *reinterpret_cast<const float4*>(
                Wv + (size_t)(o0 + o) * 256 + kt + c4);
            Bs[c4 + 0][o] = v.x; Bs[c4 + 1][o] = v.y;
            Bs[c4 + 2][o] = v.z; Bs[c4 + 3][o] = v.w;
        }
        __syncthreads();

        #pragma unroll 8
        for (int kk = 0; kk < 64; ++kk) {
            const float4 a4 = *reinterpret_cast<const float4*>(&As[kk][tp]);
            const float4 b4 = *reinterpret_cast<const float4*>(&Bs[kk][to]);
            const float av[4] = {a4.x, a4.y, a4.z, a4.w};
            const float bw[4] = {b4.x, b4.y, b4.z, b4.w};
            #pragma unroll
            for (int i = 0; i < 4; ++i)
                #pragma unroll
                for (int j = 0; j < 4; ++j)
                    acc[i][j] = fmaf(av[i], bw[j], acc[i][j]);
        }
        __syncthreads();
    }

    const int oc = o0 + to;
    float4 bb = *reinterpret_cast<const float4*>(bv + oc);
    #pragma unroll
    for (int i = 0; i < 4; ++i) {
        int p = tp + i;
        if (p0 + p >= HW) continue;
        float4 r;
        r.x = acc[i][0] + bb.x;
        r.y = acc[i][1] + bb.y;
        r.z = acc[i][2] + bb.z;
        r.w = acc[i][3] + bb.w;
        size_t pix = (size_t)b * P_ + offs[lvl] + p0 + p;
        *reinterpret_cast<float4*>(proj + pix * 256 + oc) = r;
    }
}

// ---------------------------------------------------------------------------
// Sampling + attention-weighted accumulation.
// Block = one (b,q); thread = (head m = t/32, channel d = t%32).
// out2[bq, m*32+d] = sum_{l,k} attn * bilinear(proj)
// ---------------------------------------------------------------------------
__global__ __launch_bounds__(256) void sample_kernel(
    const float* __restrict__ S,       // [B*NQ, 288]: 192 offsets + 96 logits
    const float* __restrict__ refp,    // [B*NQ, 2]
    const float* __restrict__ proj,    // [B, P_, 256]
    float* __restrict__ out2)          // [B*NQ, 256]
{
    constexpr int Wd[3]   = {100, 50, 25};
    constexpr int Hd[3]   = {100, 50, 25};
    constexpr int offs[3] = {0, 10000, 12500};

    const int bq = blockIdx.x;
    const int b  = bq / NQ_;
    const int t  = threadIdx.x;
    const int m  = t >> 5;
    const int d  = t & 31;

    const float refx = refp[(size_t)bq * 2 + 0];
    const float refy = refp[(size_t)bq * 2 + 1];
    const float* Sq = S + (size_t)bq * 288;

    // softmax over the 12 logits of this head (redundant across the 32 lanes)
    float w[12];
    float mx = -1e30f;
    #pragma unroll
    for (int j = 0; j < 12; ++j) {
        w[j] = Sq[192 + m * 12 + j];
        mx = fmaxf(mx, w[j]);
    }
    float sum = 0.f;
    #pragma unroll
    for (int j = 0; j < 12; ++j) {
        w[j] = __expf(w[j] - mx);
        sum += w[j];
    }
    const float inv = 1.f / sum;

    const float* projb = proj + (size_t)b * P_ * 256;
    float acc = 0.f;

    #pragma unroll
    for (int l = 0; l < 3; ++l) {
        const int Wl = Wd[l], Hl = Hd[l], base = offs[l];
        #pragma unroll
        for (int k = 0; k < 4; ++k) {
            const float ox = Sq[((m * 3 + l) * 4 + k) * 2 + 0];
            const float oy = Sq[((m * 3 + l) * 4 + k) * 2 + 1];
            // (ref + off/norm)*size - 0.5  ==  ref*size + off - 0.5
            const float px = refx * (float)Wl + ox - 0.5f;
            const float py = refy * (float)Hl + oy - 0.5f;
            const float x0f = floorf(px), y0f = floorf(py);
            const float wx1 = px - x0f, wy1 = py - y0f;
            const float wx0 = 1.f - wx1, wy0 = 1.f - wy1;
            const int x0 = (int)x0f, y0 = (int)y0f;
            const int x1 = x0 + 1, y1 = y0 + 1;

            const int ch = m * 32 + d;
            float v00 = 0.f, v10 = 0.f, v01 = 0.f, v11 = 0.f;
            const bool vx0 = (unsigned)x0 < (unsigned)Wl;
            const bool vx1 = (unsigned)x1 < (unsigned)Wl;
            const bool vy0 = (unsigned)y0 < (unsigned)Hl;
            const bool vy1 = (unsigned)y1 < (unsigned)Hl;
            if (vy0) {
                const float* row = projb + ((size_t)(base + y0 * Wl)) * 256;
                if (vx0) v00 = row[(size_t)x0 * 256 + ch];
                if (vx1) v10 = row[(size_t)x1 * 256 + ch];
            }
            if (vy1) {
                const float* row = projb + ((size_t)(base + y1 * Wl)) * 256;
                if (vx0) v01 = row[(size_t)x0 * 256 + ch];
                if (vx1) v11 = row[(size_t)x1 * 256 + ch];
            }
            const float samp = wx0 * wy0 * v00 + wx1 * wy0 * v10
                             + wx0 * wy1 * v01 + wx1 * wy1 * v11;
            acc = fmaf(w[l * 4 + k] * inv, samp, acc);
        }
    }
    out2[(size_t)bq * 256 + t] = acc;
}

// ---------------------------------------------------------------------------
extern "C" void kernel_launch(void* const* d_in, const int* in_sizes, int n_in,
                              void* d_out, int out_size, void* d_ws, size_t ws_size,
                              hipStream_t stream)
{
    const float* query = (const float*)d_in[0];
    const float* refp  = (const float*)d_in[1];
    const float* v0    = (const float*)d_in[2];
    const float* v1    = (const float*)d_in[3];
    const float* v2    = (const float*)d_in[4];
    const float* Wv    = (const float*)d_in[5];
    const float* bv    = (const float*)d_in[6];
    const float* Ws    = (const float*)d_in[7];
    const float* bs    = (const float*)d_in[8];
    const float* Wa    = (const float*)d_in[9];
    const float* ba    = (const float*)d_in[10];
    const float* Wo    = (const float*)d_in[11];
    const float* bo    = (const float*)d_in[12];
    float* out = (float*)d_out;

    float* proj = (float*)d_ws;                          // B*P*256   = 6.72M f
    float* S    = proj + (size_t)B_ * P_ * 256;          // B*NQ*288  = 5.76M f
    float* out2 = S    + (size_t)B_ * NQ_ * 288;         // B*NQ*256  = 5.12M f

    dim3 blk(256);

    // 1) value projection -> proj[b][pixel][256]
    proj_kernel<<<dim3(157, 4, 6), blk, 0, stream>>>(v0, v1, v2, Wv, bv, proj);

    // 2) offsets (192) + attention logits (96) -> S[b*NQ][288]
    gemm_rowA<<<dim3(313, 5), blk, 0, stream>>>(
        query, B_ * NQ_, Ws, bs, 192, Wa, ba, 288, S);

    // 3) softmax + bilinear sampling -> out2[b*NQ][256]
    sample_kernel<<<dim3(B_ * NQ_), blk, 0, stream>>>(S, refp, proj, out2);

    // 4) output projection -> d_out
    gemm_rowA<<<dim3(313, 4), blk, 0, stream>>>(
        out2, B_ * NQ_, Wo, bo, 256, nullptr, nullptr, 256, out);
}

// Round 2
// 343.335 us; speedup vs baseline: 1.3587x; 1.3587x over previous
//
#include <hip/hip_runtime.h>
#include <cstddef>

#define B_ 2
#define NQ_ 10000
#define C_ 256
#define M_ 8
#define L_ 3
#define K_ 4
#define D_ 32
#define P_ 13125   // 10000 + 2500 + 625

typedef unsigned short u16;
typedef __attribute__((ext_vector_type(8))) short short8;
typedef __attribute__((ext_vector_type(4))) float f32x4;

static __device__ __forceinline__ u16 f2bf(float f) {
    union { float f; unsigned u; } x; x.f = f;
    unsigned r = x.u + 0x7fffu + ((x.u >> 16) & 1u);   // RNE
    return (u16)(r >> 16);
}

// ---------------------------------------------------------------------------
// query f32 -> bf16 (vectorized, 4/thread). n = 20000*256.
// ---------------------------------------------------------------------------
__global__ __launch_bounds__(256) void cvt_query(
    const float* __restrict__ src, u16* __restrict__ dst)
{
    const int i4 = (blockIdx.x * 256 + threadIdx.x) * 4;
    float4 v = *reinterpret_cast<const float4*>(src + i4);
    ushort4 o;
    o.x = f2bf(v.x); o.y = f2bf(v.y); o.z = f2bf(v.z); o.w = f2bf(v.w);
    *reinterpret_cast<ushort4*>(dst + i4) = o;
}

// ---------------------------------------------------------------------------
// Weights f32 -> bf16. Segments: Wv(256r) -> Wvbf, Ws(192r)+Wa(96r) -> WsWabf
// (concatenated), Wo(256r) -> Wobf. One thread per element; 800 blocks.
// ---------------------------------------------------------------------------
__global__ __launch_bounds__(256) void cvt_weights(
    const float* __restrict__ Wv, const float* __restrict__ Ws,
    const float* __restrict__ Wa, const float* __restrict__ Wo,
    u16* __restrict__ Wvbf, u16* __restrict__ WsWabf, u16* __restrict__ Wobf)
{
    const int i = blockIdx.x * 256 + threadIdx.x;   // 0 .. 204799
    if (i < 65536) {
        Wvbf[i] = f2bf(Wv[i]);
    } else if (i < 65536 + 73728) {                  // 288 rows of Ws||Wa
        int j = i - 65536;
        WsWabf[j] = f2bf(j < 49152 ? Ws[j] : Wa[j - 49152]);
    } else {
        int j = i - (65536 + 73728);
        Wobf[j] = f2bf(Wo[j]);
    }
}

// ---------------------------------------------------------------------------
// value [b][c][p] f32  ->  Vt [b][pixel][c] bf16 (pixel-major, level-offset)
// 64x64 LDS transpose tile, pad 66 (lane*33 % 32 = 2 lanes/bank = free).
// ---------------------------------------------------------------------------
__global__ __launch_bounds__(256) void transpose_value(
    const float* __restrict__ v0, const float* __restrict__ v1,
    const float* __restrict__ v2, u16* __restrict__ Vt)
{
    constexpr int HWs[3]  = {10000, 2500, 625};
    constexpr int offs[3] = {0, 10000, 12500};

    const int z   = blockIdx.z;
    const int b   = z / 3;
    const int lvl = z % 3;
    const int HW  = HWs[lvl];
    const int p0  = blockIdx.x * 64;
    if (p0 >= HW) return;
    const int c0  = blockIdx.y * 64;

    const float* V = (lvl == 0 ? v0 : (lvl == 1 ? v1 : v2)) + (size_t)b * 256 * HW;

    __shared__ u16 tile[64][66];
    const int t  = threadIdx.x;
    const int pl = t & 63;
    const int cb = t >> 6;   // 0..3

    #pragma unroll
    for (int i = 0; i < 16; ++i) {
        int c = cb + i * 4;
        float vv = 0.f;
        if (p0 + pl < HW)
            vv = V[(size_t)(c0 + c) * HW + p0 + pl];
        tile[pl][c] = f2bf(vv);
    }
    __syncthreads();

    const int cl = t & 63;
    const int pb = t >> 6;
    #pragma unroll
    for (int i = 0; i < 16; ++i) {
        int p = pb + i * 4;
        if (p0 + p < HW)
            Vt[((size_t)b * P_ + offs[lvl] + p0 + p) * 256 + c0 + cl] = tile[p][cl];
    }
}

// ---------------------------------------------------------------------------
// bf16 MFMA GEMM:  Cout[rows, Ntot] = A[rows,256](bf16) @ Bw[Ntot,256](bf16)^T
//                  + bias (f32).  16x16x32 MFMA, LDS-free fragment loads.
// Block 256 thr = 4 waves; block tile 128x64; wave tile 32x64
// (2 row-tiles x 4 col-tiles of 16x16). Fragment loads are 16B, and a wave's
// 64 lanes cover 16 rows x 64B contiguous -> full-line utilization.
// ---------------------------------------------------------------------------
__global__ __launch_bounds__(256) void gemm_bf16(
    const u16* __restrict__ A, int rows,
    const u16* __restrict__ Bw,
    const float* __restrict__ bias1, int N1,
    const float* __restrict__ bias2, int Ntot,
    float* __restrict__ Cout)
{
    const int t  = threadIdx.x;
    const int w  = t >> 6;
    const int l  = t & 63;
    const int row0 = blockIdx.x * 128 + w * 32;
    const int o0   = blockIdx.y * 64;
    const int lr = l & 15;
    const int kb = (l >> 4) * 8;

    // clamped indices: no OOB reads; garbage rows/cols never stored
    const int ra0 = min(row0 + lr,      rows - 1);
    const int ra1 = min(row0 + 16 + lr, rows - 1);
    const u16* Ap0 = A + (size_t)ra0 * 256 + kb;
    const u16* Ap1 = A + (size_t)ra1 * 256 + kb;
    const u16* Bp[4];
    #pragma unroll
    for (int ct = 0; ct < 4; ++ct) {
        int cbr = min(o0 + ct * 16 + lr, Ntot - 1);
        Bp[ct] = Bw + (size_t)cbr * 256 + kb;
    }

    f32x4 acc[2][4] = {};

    #pragma unroll
    for (int k0 = 0; k0 < 256; k0 += 32) {
        short8 a0 = *reinterpret_cast<const short8*>(Ap0 + k0);
        short8 a1 = *reinterpret_cast<const short8*>(Ap1 + k0);
        short8 b0 = *reinterpret_cast<const short8*>(Bp[0] + k0);
        short8 b1 = *reinterpret_cast<const short8*>(Bp[1] + k0);
        short8 b2 = *reinterpret_cast<const short8*>(Bp[2] + k0);
        short8 b3 = *reinterpret_cast<const short8*>(Bp[3] + k0);
        acc[0][0] = __builtin_amdgcn_mfma_f32_16x16x32_bf16(a0, b0, acc[0][0], 0, 0, 0);
        acc[0][1] = __builtin_amdgcn_mfma_f32_16x16x32_bf16(a0, b1, acc[0][1], 0, 0, 0);
        acc[0][2] = __builtin_amdgcn_mfma_f32_16x16x32_bf16(a0, b2, acc[0][2], 0, 0, 0);
        acc[0][3] = __builtin_amdgcn_mfma_f32_16x16x32_bf16(a0, b3, acc[0][3], 0, 0, 0);
        acc[1][0] = __builtin_amdgcn_mfma_f32_16x16x32_bf16(a1, b0, acc[1][0], 0, 0, 0);
        acc[1][1] = __builtin_amdgcn_mfma_f32_16x16x32_bf16(a1, b1, acc[1][1], 0, 0, 0);
        acc[1][2] = __builtin_amdgcn_mfma_f32_16x16x32_bf16(a1, b2, acc[1][2], 0, 0, 0);
        acc[1][3] = __builtin_amdgcn_mfma_f32_16x16x32_bf16(a1, b3, acc[1][3], 0, 0, 0);
    }

    // Epilogue: C/D layout col = l&15, row = (l>>4)*4 + reg  [m89-verified]
    const int orow = (l >> 4) * 4;
    #pragma unroll
    for (int ct = 0; ct < 4; ++ct) {
        const int col = o0 + ct * 16 + lr;
        if (col >= Ntot) continue;
        const float bsv = (col < N1) ? bias1[col] : bias2[col - N1];
        #pragma unroll
        for (int rt = 0; rt < 2; ++rt) {
            #pragma unroll
            for (int r = 0; r < 4; ++r) {
                const int row = row0 + rt * 16 + orow + r;
                if (row < rows)
                    Cout[(size_t)row * Ntot + col] = acc[rt][ct][r] + bsv;
            }
        }
    }
}

// ---------------------------------------------------------------------------
// Sampling + attention-weighted accumulation (unchanged logic; bf16 output).
// Block = one (b,q); thread = (head m = t/32, channel d = t%32).
// ---------------------------------------------------------------------------
__global__ __launch_bounds__(256) void sample_kernel(
    const float* __restrict__ S,       // [B*NQ, 288]: 192 offsets + 96 logits
    const float* __restrict__ refp,    // [B*NQ, 2]
    const float* __restrict__ proj,    // [B, P_, 256]
    u16* __restrict__ out2)            // [B*NQ, 256] bf16
{
    constexpr int Wd[3]   = {100, 50, 25};
    constexpr int Hd[3]   = {100, 50, 25};
    constexpr int offs[3] = {0, 10000, 12500};

    const int bq = blockIdx.x;
    const int b  = bq / NQ_;
    const int t  = threadIdx.x;
    const int m  = t >> 5;
    const int d  = t & 31;

    const float refx = refp[(size_t)bq * 2 + 0];
    const float refy = refp[(size_t)bq * 2 + 1];
    const float* Sq = S + (size_t)bq * 288;

    float w[12];
    float mx = -1e30f;
    #pragma unroll
    for (int j = 0; j < 12; ++j) {
        w[j] = Sq[192 + m * 12 + j];
        mx = fmaxf(mx, w[j]);
    }
    float sum = 0.f;
    #pragma unroll
    for (int j = 0; j < 12; ++j) {
        w[j] = __expf(w[j] - mx);
        sum += w[j];
    }
    const float inv = 1.f / sum;

    const float* projb = proj + (size_t)b * P_ * 256;
    float acc = 0.f;

    #pragma unroll
    for (int l = 0; l < 3; ++l) {
        const int Wl = Wd[l], Hl = Hd[l], base = offs[l];
        #pragma unroll
        for (int k = 0; k < 4; ++k) {
            const float ox = Sq[((m * 3 + l) * 4 + k) * 2 + 0];
            const float oy = Sq[((m * 3 + l) * 4 + k) * 2 + 1];
            const float px = refx * (float)Wl + ox - 0.5f;
            const float py = refy * (float)Hl + oy - 0.5f;
            const float x0f = floorf(px), y0f = floorf(py);
            const float wx1 = px - x0f, wy1 = py - y0f;
            const float wx0 = 1.f - wx1, wy0 = 1.f - wy1;
            const int x0 = (int)x0f, y0 = (int)y0f;
            const int x1 = x0 + 1, y1 = y0 + 1;

            const int ch = m * 32 + d;
            float v00 = 0.f, v10 = 0.f, v01 = 0.f, v11 = 0.f;
            const bool vx0 = (unsigned)x0 < (unsigned)Wl;
            const bool vx1 = (unsigned)x1 < (unsigned)Wl;
            const bool vy0 = (unsigned)y0 < (unsigned)Hl;
            const bool vy1 = (unsigned)y1 < (unsigned)Hl;
            if (vy0) {
                const float* row = projb + ((size_t)(base + y0 * Wl)) * 256;
                if (vx0) v00 = row[(size_t)x0 * 256 + ch];
                if (vx1) v10 = row[(size_t)x1 * 256 + ch];
            }
            if (vy1) {
                const float* row = projb + ((size_t)(base + y1 * Wl)) * 256;
                if (vx0) v01 = row[(size_t)x0 * 256 + ch];
                if (vx1) v11 = row[(size_t)x1 * 256 + ch];
            }
            const float samp = wx0 * wy0 * v00 + wx1 * wy0 * v10
                             + wx0 * wy1 * v01 + wx1 * wy1 * v11;
            acc = fmaf(w[l * 4 + k] * inv, samp, acc);
        }
    }
    out2[(size_t)bq * 256 + t] = f2bf(acc);
}

// ---------------------------------------------------------------------------
extern "C" void kernel_launch(void* const* d_in, const int* in_sizes, int n_in,
                              void* d_out, int out_size, void* d_ws, size_t ws_size,
                              hipStream_t stream)
{
    const float* query = (const float*)d_in[0];
    const float* refp  = (const float*)d_in[1];
    const float* v0    = (const float*)d_in[2];
    const float* v1    = (const float*)d_in[3];
    const float* v2    = (const float*)d_in[4];
    const float* Wv    = (const float*)d_in[5];
    const float* bv    = (const float*)d_in[6];
    const float* Ws    = (const float*)d_in[7];
    const float* bs    = (const float*)d_in[8];
    const float* Wa    = (const float*)d_in[9];
    const float* ba    = (const float*)d_in[10];
    const float* Wo    = (const float*)d_in[11];
    const float* bo    = (const float*)d_in[12];
    float* out = (float*)d_out;

    // workspace layout (bytes): proj f32 26.88M | S f32 23.04M | Vt bf16 13.44M
    //                           | qbf/out2bf bf16 10.24M (aliased) | weights bf16
    char* wsb = (char*)d_ws;
    float* proj  = (float*)wsb;                                  wsb += (size_t)B_ * P_ * 256 * 4;
    float* S     = (float*)wsb;                                  wsb += (size_t)B_ * NQ_ * 288 * 4;
    u16*   Vt    = (u16*)wsb;                                    wsb += (size_t)B_ * P_ * 256 * 2;
    u16*   qbf   = (u16*)wsb;                                    // also reused as out2bf
    u16*   out2bf = qbf;                                         wsb += (size_t)B_ * NQ_ * 256 * 2;
    u16*   Wvbf  = (u16*)wsb;                                    wsb += 65536 * 2;
    u16*   WsWabf= (u16*)wsb;                                    wsb += 73728 * 2;
    u16*   Wobf  = (u16*)wsb;                                    wsb += 65536 * 2;

    dim3 blk(256);

    // 0) conversions
    cvt_query<<<dim3((B_ * NQ_ * 256) / 1024), blk, 0, stream>>>(query, qbf);
    cvt_weights<<<dim3(800), blk, 0, stream>>>(Wv, Ws, Wa, Wo, Wvbf, WsWabf, Wobf);
    transpose_value<<<dim3(157, 4, 6), blk, 0, stream>>>(v0, v1, v2, Vt);

    // 1) value projection: proj[b*P+p][256] = Vt @ Wv^T + bv
    gemm_bf16<<<dim3((B_ * P_ + 127) / 128, 4), blk, 0, stream>>>(
        Vt, B_ * P_, Wvbf, bv, 256, bv, 256, proj);

    // 2) offsets+logits: S[b*NQ][288] = qbf @ (Ws||Wa)^T + (bs||ba)
    gemm_bf16<<<dim3((B_ * NQ_ + 127) / 128, 5), blk, 0, stream>>>(
        qbf, B_ * NQ_, WsWabf, bs, 192, ba, 288, S);

    // 3) softmax + bilinear sampling -> out2 (bf16)
    sample_kernel<<<dim3(B_ * NQ_), blk, 0, stream>>>(S, refp, proj, out2bf);

    // 4) output projection -> d_out
    gemm_bf16<<<dim3((B_ * NQ_ + 127) / 128, 4), blk, 0, stream>>>(
        out2bf, B_ * NQ_, Wobf, bo, 256, bo, 256, out);
}

// Round 3
// 211.397 us; speedup vs baseline: 2.2067x; 1.6241x over previous
//
#include <hip/hip_runtime.h>
#include <cstddef>

#define B_ 2
#define NQ_ 10000
#define C_ 256
#define M_ 8
#define L_ 3
#define K_ 4
#define D_ 32
#define P_ 13125   // 10000 + 2500 + 625

typedef unsigned short u16;
typedef __attribute__((ext_vector_type(8))) short short8;
typedef __attribute__((ext_vector_type(4))) float f32x4;

static __device__ __forceinline__ u16 f2bf(float f) {
    union { float f; unsigned u; } x; x.f = f;
    unsigned r = x.u + 0x7fffu + ((x.u >> 16) & 1u);   // RNE
    return (u16)(r >> 16);
}
static __device__ __forceinline__ float bf2f(u16 u) {
    union { unsigned u; float f; } x; x.u = (unsigned)u << 16;
    return x.f;
}

// ---------------------------------------------------------------------------
// All f32->bf16 conversions in one kernel.
// Blocks [0,5000): query (5.12M elems, 4/thread).
// Blocks [5000,5200): weights Wv | Ws||Wa | Wo (204800 elems, 4/thread).
// ---------------------------------------------------------------------------
__global__ __launch_bounds__(256) void cvt_all(
    const float* __restrict__ query,
    const float* __restrict__ Wv, const float* __restrict__ Ws,
    const float* __restrict__ Wa, const float* __restrict__ Wo,
    u16* __restrict__ qbf, u16* __restrict__ Wvbf,
    u16* __restrict__ WsWabf, u16* __restrict__ Wobf)
{
    const int bx = blockIdx.x;
    if (bx < 5000) {
        const int i4 = (bx * 256 + threadIdx.x) * 4;
        float4 v = *reinterpret_cast<const float4*>(query + i4);
        ushort4 o;
        o.x = f2bf(v.x); o.y = f2bf(v.y); o.z = f2bf(v.z); o.w = f2bf(v.w);
        *reinterpret_cast<ushort4*>(qbf + i4) = o;
        return;
    }
    const int j4 = ((bx - 5000) * 256 + threadIdx.x) * 4;   // 0..204796
    const float* src;
    u16* dst;
    int off;
    if (j4 < 65536)        { src = Wv; dst = Wvbf; off = j4; }
    else if (j4 < 139264)  {
        int j = j4 - 65536;
        if (j < 49152) { src = Ws; off = j; }
        else           { src = Wa; off = j - 49152; }
        dst = WsWabf + (j - off);   // dst base shift so dst[off+...] lands at j
        dst = WsWabf; off = j;      // simpler: recompute below
        src = (j < 49152) ? Ws : Wa;
        float4 v = *reinterpret_cast<const float4*>(
            ((j < 49152) ? Ws + j : Wa + (j - 49152)));
        ushort4 o;
        o.x = f2bf(v.x); o.y = f2bf(v.y); o.z = f2bf(v.z); o.w = f2bf(v.w);
        *reinterpret_cast<ushort4*>(WsWabf + j) = o;
        return;
    }
    else                   { src = Wo; dst = Wobf; off = j4 - 139264; }
    float4 v = *reinterpret_cast<const float4*>(src + off);
    ushort4 o;
    o.x = f2bf(v.x); o.y = f2bf(v.y); o.z = f2bf(v.z); o.w = f2bf(v.w);
    *reinterpret_cast<ushort4*>(dst + off) = o;
}

// ---------------------------------------------------------------------------
// value [b][c][p] f32  ->  Vt [b][pixel][c] bf16 (pixel-major, level-offset)
// ---------------------------------------------------------------------------
__global__ __launch_bounds__(256) void transpose_value(
    const float* __restrict__ v0, const float* __restrict__ v1,
    const float* __restrict__ v2, u16* __restrict__ Vt)
{
    constexpr int HWs[3]  = {10000, 2500, 625};
    constexpr int offs[3] = {0, 10000, 12500};

    const int z   = blockIdx.z;
    const int b   = z / 3;
    const int lvl = z % 3;
    const int HW  = HWs[lvl];
    const int p0  = blockIdx.x * 64;
    if (p0 >= HW) return;
    const int c0  = blockIdx.y * 64;

    const float* V = (lvl == 0 ? v0 : (lvl == 1 ? v1 : v2)) + (size_t)b * 256 * HW;

    __shared__ u16 tile[64][66];
    const int t  = threadIdx.x;
    const int pl = t & 63;
    const int cb = t >> 6;   // 0..3

    #pragma unroll
    for (int i = 0; i < 16; ++i) {
        int c = cb + i * 4;
        float vv = 0.f;
        if (p0 + pl < HW)
            vv = V[(size_t)(c0 + c) * HW + p0 + pl];
        tile[pl][c] = f2bf(vv);
    }
    __syncthreads();

    const int cl = t & 63;
    const int pb = t >> 6;
    #pragma unroll
    for (int i = 0; i < 16; ++i) {
        int p = pb + i * 4;
        if (p0 + p < HW)
            Vt[((size_t)b * P_ + offs[lvl] + p0 + p) * 256 + c0 + cl] = tile[p][cl];
    }
}

// ---------------------------------------------------------------------------
// bf16 MFMA GEMM with B panel staged in LDS.
// Cout[rows, Ntot] = A[rows,256] @ Bw[Ntot,256]^T + bias; OutT = float or u16.
// Block 256 thr = 4 waves; block tile 128x64; wave tile 32x64.
// Bs layout: col-local * 264 + k (u16), pad 8 -> ds_read_b128 at 2-way
// bank aliasing (free). K-loop: 2 global A-fragment loads + 4 ds_read_b128
// + 8 MFMA per 32-k step, fully unrolled.
// ---------------------------------------------------------------------------
template <typename OutT>
__global__ __launch_bounds__(256) void gemm_bf16(
    const u16* __restrict__ A, int rows,
    const u16* __restrict__ Bw,
    const float* __restrict__ bias1, int N1,
    const float* __restrict__ bias2, int Ntot,
    OutT* __restrict__ Cout)
{
    __shared__ u16 Bs[64 * 264];

    const int t  = threadIdx.x;
    const int w  = t >> 6;
    const int l  = t & 63;
    const int row0 = blockIdx.x * 128 + w * 32;
    const int o0   = blockIdx.y * 64;
    const int lr = l & 15;
    const int kb = (l >> 4) * 8;

    // stage B panel: 64 cols x 256 k
    #pragma unroll
    for (int i = 0; i < 8; ++i) {
        int idx = i * 256 + t;          // 0..2047 short8-chunks
        int col = idx >> 5;             // 0..63
        int kc  = (idx & 31) * 8;       // 0..248
        int colg = min(o0 + col, Ntot - 1);
        short8 v = *reinterpret_cast<const short8*>(Bw + (size_t)colg * 256 + kc);
        *reinterpret_cast<short8*>(&Bs[col * 264 + kc]) = v;
    }

    const int ra0 = min(row0 + lr,      rows - 1);
    const int ra1 = min(row0 + 16 + lr, rows - 1);
    const u16* Ap0 = A + (size_t)ra0 * 256 + kb;
    const u16* Ap1 = A + (size_t)ra1 * 256 + kb;

    __syncthreads();

    f32x4 acc[2][4] = {};

    #pragma unroll
    for (int k0 = 0; k0 < 256; k0 += 32) {
        short8 a0 = *reinterpret_cast<const short8*>(Ap0 + k0);
        short8 a1 = *reinterpret_cast<const short8*>(Ap1 + k0);
        short8 b0 = *reinterpret_cast<const short8*>(&Bs[(0 * 16 + lr) * 264 + kb + k0]);
        short8 b1 = *reinterpret_cast<const short8*>(&Bs[(1 * 16 + lr) * 264 + kb + k0]);
        short8 b2 = *reinterpret_cast<const short8*>(&Bs[(2 * 16 + lr) * 264 + kb + k0]);
        short8 b3 = *reinterpret_cast<const short8*>(&Bs[(3 * 16 + lr) * 264 + kb + k0]);
        acc[0][0] = __builtin_amdgcn_mfma_f32_16x16x32_bf16(a0, b0, acc[0][0], 0, 0, 0);
        acc[0][1] = __builtin_amdgcn_mfma_f32_16x16x32_bf16(a0, b1, acc[0][1], 0, 0, 0);
        acc[0][2] = __builtin_amdgcn_mfma_f32_16x16x32_bf16(a0, b2, acc[0][2], 0, 0, 0);
        acc[0][3] = __builtin_amdgcn_mfma_f32_16x16x32_bf16(a0, b3, acc[0][3], 0, 0, 0);
        acc[1][0] = __builtin_amdgcn_mfma_f32_16x16x32_bf16(a1, b0, acc[1][0], 0, 0, 0);
        acc[1][1] = __builtin_amdgcn_mfma_f32_16x16x32_bf16(a1, b1, acc[1][1], 0, 0, 0);
        acc[1][2] = __builtin_amdgcn_mfma_f32_16x16x32_bf16(a1, b2, acc[1][2], 0, 0, 0);
        acc[1][3] = __builtin_amdgcn_mfma_f32_16x16x32_bf16(a1, b3, acc[1][3], 0, 0, 0);
    }

    // C/D layout: col = l&15, row = (l>>4)*4 + reg  [m89-verified]
    const int orow = (l >> 4) * 4;
    #pragma unroll
    for (int ct = 0; ct < 4; ++ct) {
        const int col = o0 + ct * 16 + lr;
        if (col >= Ntot) continue;
        const float bsv = (col < N1) ? bias1[col] : bias2[col - N1];
        #pragma unroll
        for (int rt = 0; rt < 2; ++rt) {
            #pragma unroll
            for (int r = 0; r < 4; ++r) {
                const int row = row0 + rt * 16 + orow + r;
                if (row < rows) {
                    float val = acc[rt][ct][r] + bsv;
                    if constexpr (sizeof(OutT) == 2)
                        Cout[(size_t)row * Ntot + col] = (OutT)f2bf(val);
                    else
                        Cout[(size_t)row * Ntot + col] = (OutT)val;
                }
            }
        }
    }
}

// ---------------------------------------------------------------------------
// Sampling. Phase 1 (threads 0..95): per (head m, point j) compute softmax
// weight, 4 corner indices and premultiplied bilinear weights -> LDS.
// Phase 2 (all 256): per channel, 12 x (4 bf16 gathers + 4 fma).
// ---------------------------------------------------------------------------
__global__ __launch_bounds__(256) void sample_kernel(
    const float* __restrict__ S,       // [B*NQ, 288]
    const float* __restrict__ refp,    // [B*NQ, 2]
    const u16* __restrict__ proj,      // [B, P_, 256] bf16
    u16* __restrict__ out2)            // [B*NQ, 256] bf16
{
    constexpr int Wd[3]   = {100, 50, 25};
    constexpr int offs[3] = {0, 10000, 12500};

    __shared__ int   midx[96][4];
    __shared__ float mw[96][4];

    const int bq = blockIdx.x;
    const int b  = bq / NQ_;
    const int t  = threadIdx.x;

    if (t < 96) {
        const int tm = t / 12;       // head
        const int tj = t % 12;       // point = l*4+k
        const float* Sq = S + (size_t)bq * 288;
        // softmax over head tm's 12 logits (redundant x12, tiny)
        float lg[12], mx = -1e30f;
        #pragma unroll
        for (int jj = 0; jj < 12; ++jj) {
            lg[jj] = Sq[192 + tm * 12 + jj];
            mx = fmaxf(mx, lg[jj]);
        }
        float sum = 0.f;
        #pragma unroll
        for (int jj = 0; jj < 12; ++jj) sum += __expf(lg[jj] - mx);
        const float attn = __expf(lg[tj] - mx) / sum;

        const int l  = tj >> 2;
        const int Wl = Wd[l];
        const float refx = refp[(size_t)bq * 2 + 0];
        const float refy = refp[(size_t)bq * 2 + 1];
        const float ox = Sq[(tm * 12 + tj) * 2 + 0];
        const float oy = Sq[(tm * 12 + tj) * 2 + 1];
        const float px = refx * (float)Wl + ox - 0.5f;   // H==W per level
        const float py = refy * (float)Wl + oy - 0.5f;
        const float x0f = floorf(px), y0f = floorf(py);
        const float wx1 = px - x0f, wy1 = py - y0f;
        const float wx0 = 1.f - wx1, wy0 = 1.f - wy1;
        const int x0 = (int)x0f, y0 = (int)y0f;
        const int x1 = x0 + 1, y1 = y0 + 1;
        const bool vx0 = (unsigned)x0 < (unsigned)Wl;
        const bool vx1 = (unsigned)x1 < (unsigned)Wl;
        const bool vy0 = (unsigned)y0 < (unsigned)Wl;
        const bool vy1 = (unsigned)y1 < (unsigned)Wl;
        const int chb = tm * 32;
        const int base = offs[l];
        midx[t][0] = (vx0 && vy0) ? ((base + y0 * Wl + x0) * 256 + chb) : 0;
        midx[t][1] = (vx1 && vy0) ? ((base + y0 * Wl + x1) * 256 + chb) : 0;
        midx[t][2] = (vx0 && vy1) ? ((base + y1 * Wl + x0) * 256 + chb) : 0;
        midx[t][3] = (vx1 && vy1) ? ((base + y1 * Wl + x1) * 256 + chb) : 0;
        mw[t][0] = (vx0 && vy0) ? attn * wx0 * wy0 : 0.f;
        mw[t][1] = (vx1 && vy0) ? attn * wx1 * wy0 : 0.f;
        mw[t][2] = (vx0 && vy1) ? attn * wx0 * wy1 : 0.f;
        mw[t][3] = (vx1 && vy1) ? attn * wx1 * wy1 : 0.f;
    }
    __syncthreads();

    const int m = t >> 5;
    const int d = t & 31;
    const u16* projb = proj + (size_t)b * P_ * 256;
    float acc = 0.f;

    #pragma unroll
    for (int j = 0; j < 12; ++j) {
        const int mj = m * 12 + j;
        const int4   o  = *reinterpret_cast<const int4*>(midx[mj]);
        const float4 ww = *reinterpret_cast<const float4*>(mw[mj]);
        const float v00 = bf2f(projb[o.x + d]);
        const float v10 = bf2f(projb[o.y + d]);
        const float v01 = bf2f(projb[o.z + d]);
        const float v11 = bf2f(projb[o.w + d]);
        acc = fmaf(ww.x, v00, acc);
        acc = fmaf(ww.y, v10, acc);
        acc = fmaf(ww.z, v01, acc);
        acc = fmaf(ww.w, v11, acc);
    }
    out2[(size_t)bq * 256 + t] = f2bf(acc);
}

// ---------------------------------------------------------------------------
extern "C" void kernel_launch(void* const* d_in, const int* in_sizes, int n_in,
                              void* d_out, int out_size, void* d_ws, size_t ws_size,
                              hipStream_t stream)
{
    const float* query = (const float*)d_in[0];
    const float* refp  = (const float*)d_in[1];
    const float* v0    = (const float*)d_in[2];
    const float* v1    = (const float*)d_in[3];
    const float* v2    = (const float*)d_in[4];
    const float* Wv    = (const float*)d_in[5];
    const float* bv    = (const float*)d_in[6];
    const float* Ws    = (const float*)d_in[7];
    const float* bs    = (const float*)d_in[8];
    const float* Wa    = (const float*)d_in[9];
    const float* ba    = (const float*)d_in[10];
    const float* Wo    = (const float*)d_in[11];
    const float* bo    = (const float*)d_in[12];
    float* out = (float*)d_out;

    char* wsb = (char*)d_ws;
    u16*   proj  = (u16*)wsb;    wsb += (size_t)B_ * P_ * 256 * 2;   // 13.44 MB
    float* S     = (float*)wsb;  wsb += (size_t)B_ * NQ_ * 288 * 4;  // 23.04 MB
    u16*   Vt    = (u16*)wsb;    wsb += (size_t)B_ * P_ * 256 * 2;   // 13.44 MB
    u16*   qbf   = (u16*)wsb;                                         // aliased
    u16*   out2bf = qbf;         wsb += (size_t)B_ * NQ_ * 256 * 2;  // 10.24 MB
    u16*   Wvbf  = (u16*)wsb;    wsb += 65536 * 2;
    u16*   WsWabf= (u16*)wsb;    wsb += 73728 * 2;
    u16*   Wobf  = (u16*)wsb;    wsb += 65536 * 2;

    dim3 blk(256);

    cvt_all<<<dim3(5200), blk, 0, stream>>>(query, Wv, Ws, Wa, Wo,
                                            qbf, Wvbf, WsWabf, Wobf);
    transpose_value<<<dim3(157, 4, 6), blk, 0, stream>>>(v0, v1, v2, Vt);

    // 1) value projection -> proj (bf16)
    gemm_bf16<u16><<<dim3(206, 4), blk, 0, stream>>>(
        Vt, B_ * P_, Wvbf, bv, 256, bv, 256, proj);

    // 2) offsets+logits -> S (f32)
    gemm_bf16<float><<<dim3(157, 5), blk, 0, stream>>>(
        qbf, B_ * NQ_, WsWabf, bs, 192, ba, 288, S);

    // 3) softmax + bilinear sampling -> out2 (bf16)
    sample_kernel<<<dim3(B_ * NQ_), blk, 0, stream>>>(S, refp, proj, out2bf);

    // 4) output projection -> d_out (f32)
    gemm_bf16<float><<<dim3(157, 4), blk, 0, stream>>>(
        out2bf, B_ * NQ_, Wobf, bo, 256, bo, 256, out);
}

// Round 4
// 202.569 us; speedup vs baseline: 2.3029x; 1.0436x over previous
//
#include <hip/hip_runtime.h>
#include <cstddef>

#define B_ 2
#define NQ_ 10000
#define C_ 256
#define M_ 8
#define L_ 3
#define K_ 4
#define D_ 32
#define P_ 13125   // 10000 + 2500 + 625

typedef unsigned short u16;
typedef __attribute__((ext_vector_type(8))) short short8;
typedef __attribute__((ext_vector_type(4))) float f32x4;

static __device__ __forceinline__ u16 f2bf(float f) {
    union { float f; unsigned u; } x; x.f = f;
    unsigned r = x.u + 0x7fffu + ((x.u >> 16) & 1u);   // RNE
    return (u16)(r >> 16);
}
static __device__ __forceinline__ float bf2f(u16 u) {
    union { unsigned u; float f; } x; x.u = (unsigned)u << 16;
    return x.f;
}
static __device__ __forceinline__ short8 cvt8(const float4& a, const float4& b) {
    short8 r;
    r[0] = (short)f2bf(a.x); r[1] = (short)f2bf(a.y);
    r[2] = (short)f2bf(a.z); r[3] = (short)f2bf(a.w);
    r[4] = (short)f2bf(b.x); r[5] = (short)f2bf(b.y);
    r[6] = (short)f2bf(b.z); r[7] = (short)f2bf(b.w);
    return r;
}

// ---------------------------------------------------------------------------
// value [b][c][p] f32  ->  Vt [b][pixel][c] bf16 (pixel-major, level-offset)
// ---------------------------------------------------------------------------
__global__ __launch_bounds__(256) void transpose_value(
    const float* __restrict__ v0, const float* __restrict__ v1,
    const float* __restrict__ v2, u16* __restrict__ Vt)
{
    constexpr int HWs[3]  = {10000, 2500, 625};
    constexpr int offs[3] = {0, 10000, 12500};

    const int z   = blockIdx.z;
    const int b   = z / 3;
    const int lvl = z % 3;
    const int HW  = HWs[lvl];
    const int p0  = blockIdx.x * 64;
    if (p0 >= HW) return;
    const int c0  = blockIdx.y * 64;

    const float* V = (lvl == 0 ? v0 : (lvl == 1 ? v1 : v2)) + (size_t)b * 256 * HW;

    __shared__ u16 tile[64][66];
    const int t  = threadIdx.x;
    const int pl = t & 63;
    const int cb = t >> 6;   // 0..3

    #pragma unroll
    for (int i = 0; i < 16; ++i) {
        int c = cb + i * 4;
        float vv = 0.f;
        if (p0 + pl < HW)
            vv = V[(size_t)(c0 + c) * HW + p0 + pl];
        tile[pl][c] = f2bf(vv);
    }
    __syncthreads();

    const int cl = t & 63;
    const int pb = t >> 6;
    #pragma unroll
    for (int i = 0; i < 16; ++i) {
        int p = pb + i * 4;
        if (p0 + p < HW)
            Vt[((size_t)b * P_ + offs[lvl] + p0 + p) * 256 + c0 + cl] = tile[p][cl];
    }
}

// ---------------------------------------------------------------------------
// bf16 MFMA GEMM, XCD-aware 1-D grid, B staged from f32 with inline cvt.
// Cout[rows, Ntot] = A[rows,256] @ Bf[Ntot,256]^T + bias.
// bid = (rhi*npanel + panel)*8 + rlo; rowTile = rhi*8+rlo -> panel-blocks
// sharing a row stripe are 8 apart (same XCD slot, adjacent in time) so
// A re-reads across panels hit L2. Block tile 128 rows x 64 cols, 4 waves.
// A fragments loaded direct from global (bf16) or f32+cvt (AF32).
// ---------------------------------------------------------------------------
template <bool AF32, typename OutT>
__global__ __launch_bounds__(256) void gemm_panel(
    const void* __restrict__ Av, int rows, int nRowTiles, int npanel,
    const float* __restrict__ B1f, const float* __restrict__ bias1, int N1,
    const float* __restrict__ B2f, const float* __restrict__ bias2, int Ntot,
    OutT* __restrict__ Cout)
{
    __shared__ u16 Bs[64 * 264];

    const int bid  = blockIdx.x;
    const int rlo  = bid & 7;
    const int tmp  = bid >> 3;
    const int panel = tmp % npanel;
    const int rowTile = (tmp / npanel) * 8 + rlo;
    if (rowTile >= nRowTiles) return;

    const int t  = threadIdx.x;
    const int w  = t >> 6;
    const int l  = t & 63;
    const int row0 = rowTile * 128 + w * 32;
    const int o0   = panel * 64;
    const int lr = l & 15;
    const int kb = (l >> 4) * 8;

    // stage B panel: 64 cols x 256 k, f32 -> bf16
    #pragma unroll
    for (int i = 0; i < 8; ++i) {
        int idx = i * 256 + t;
        int col = idx >> 5;
        int kc  = (idx & 31) * 8;
        int colg = min(o0 + col, Ntot - 1);
        const float* Br = ((colg < N1) ? B1f + (size_t)colg * 256
                                       : B2f + (size_t)(colg - N1) * 256) + kc;
        float4 f0 = *reinterpret_cast<const float4*>(Br);
        float4 f1 = *reinterpret_cast<const float4*>(Br + 4);
        *reinterpret_cast<short8*>(&Bs[col * 264 + kc]) = cvt8(f0, f1);
    }

    const int ra0 = min(row0 + lr,      rows - 1);
    const int ra1 = min(row0 + 16 + lr, rows - 1);

    __syncthreads();

    f32x4 acc[2][4] = {};

    if constexpr (AF32) {
        const float* Af  = (const float*)Av;
        const float* Ap0 = Af + (size_t)ra0 * 256 + kb;
        const float* Ap1 = Af + (size_t)ra1 * 256 + kb;
        #pragma unroll
        for (int k0 = 0; k0 < 256; k0 += 32) {
            float4 x0 = *reinterpret_cast<const float4*>(Ap0 + k0);
            float4 y0 = *reinterpret_cast<const float4*>(Ap0 + k0 + 4);
            float4 x1 = *reinterpret_cast<const float4*>(Ap1 + k0);
            float4 y1 = *reinterpret_cast<const float4*>(Ap1 + k0 + 4);
            short8 a0 = cvt8(x0, y0);
            short8 a1 = cvt8(x1, y1);
            short8 b0 = *reinterpret_cast<const short8*>(&Bs[(0 * 16 + lr) * 264 + kb + k0]);
            short8 b1 = *reinterpret_cast<const short8*>(&Bs[(1 * 16 + lr) * 264 + kb + k0]);
            short8 b2 = *reinterpret_cast<const short8*>(&Bs[(2 * 16 + lr) * 264 + kb + k0]);
            short8 b3 = *reinterpret_cast<const short8*>(&Bs[(3 * 16 + lr) * 264 + kb + k0]);
            acc[0][0] = __builtin_amdgcn_mfma_f32_16x16x32_bf16(a0, b0, acc[0][0], 0, 0, 0);
            acc[0][1] = __builtin_amdgcn_mfma_f32_16x16x32_bf16(a0, b1, acc[0][1], 0, 0, 0);
            acc[0][2] = __builtin_amdgcn_mfma_f32_16x16x32_bf16(a0, b2, acc[0][2], 0, 0, 0);
            acc[0][3] = __builtin_amdgcn_mfma_f32_16x16x32_bf16(a0, b3, acc[0][3], 0, 0, 0);
            acc[1][0] = __builtin_amdgcn_mfma_f32_16x16x32_bf16(a1, b0, acc[1][0], 0, 0, 0);
            acc[1][1] = __builtin_amdgcn_mfma_f32_16x16x32_bf16(a1, b1, acc[1][1], 0, 0, 0);
            acc[1][2] = __builtin_amdgcn_mfma_f32_16x16x32_bf16(a1, b2, acc[1][2], 0, 0, 0);
            acc[1][3] = __builtin_amdgcn_mfma_f32_16x16x32_bf16(a1, b3, acc[1][3], 0, 0, 0);
        }
    } else {
        const u16* Af  = (const u16*)Av;
        const u16* Ap0 = Af + (size_t)ra0 * 256 + kb;
        const u16* Ap1 = Af + (size_t)ra1 * 256 + kb;
        #pragma unroll
        for (int k0 = 0; k0 < 256; k0 += 32) {
            short8 a0 = *reinterpret_cast<const short8*>(Ap0 + k0);
            short8 a1 = *reinterpret_cast<const short8*>(Ap1 + k0);
            short8 b0 = *reinterpret_cast<const short8*>(&Bs[(0 * 16 + lr) * 264 + kb + k0]);
            short8 b1 = *reinterpret_cast<const short8*>(&Bs[(1 * 16 + lr) * 264 + kb + k0]);
            short8 b2 = *reinterpret_cast<const short8*>(&Bs[(2 * 16 + lr) * 264 + kb + k0]);
            short8 b3 = *reinterpret_cast<const short8*>(&Bs[(3 * 16 + lr) * 264 + kb + k0]);
            acc[0][0] = __builtin_amdgcn_mfma_f32_16x16x32_bf16(a0, b0, acc[0][0], 0, 0, 0);
            acc[0][1] = __builtin_amdgcn_mfma_f32_16x16x32_bf16(a0, b1, acc[0][1], 0, 0, 0);
            acc[0][2] = __builtin_amdgcn_mfma_f32_16x16x32_bf16(a0, b2, acc[0][2], 0, 0, 0);
            acc[0][3] = __builtin_amdgcn_mfma_f32_16x16x32_bf16(a0, b3, acc[0][3], 0, 0, 0);
            acc[1][0] = __builtin_amdgcn_mfma_f32_16x16x32_bf16(a1, b0, acc[1][0], 0, 0, 0);
            acc[1][1] = __builtin_amdgcn_mfma_f32_16x16x32_bf16(a1, b1, acc[1][1], 0, 0, 0);
            acc[1][2] = __builtin_amdgcn_mfma_f32_16x16x32_bf16(a1, b2, acc[1][2], 0, 0, 0);
            acc[1][3] = __builtin_amdgcn_mfma_f32_16x16x32_bf16(a1, b3, acc[1][3], 0, 0, 0);
        }
    }

    // C/D layout: col = l&15, row = (l>>4)*4 + reg  [m89-verified]
    const int orow = (l >> 4) * 4;
    #pragma unroll
    for (int ct = 0; ct < 4; ++ct) {
        const int col = o0 + ct * 16 + lr;
        if (col >= Ntot) continue;
        const float bsv = (col < N1) ? bias1[col] : bias2[col - N1];
        #pragma unroll
        for (int rt = 0; rt < 2; ++rt) {
            #pragma unroll
            for (int r = 0; r < 4; ++r) {
                const int row = row0 + rt * 16 + orow + r;
                if (row < rows) {
                    float val = acc[rt][ct][r] + bsv;
                    if constexpr (sizeof(OutT) == 2)
                        Cout[(size_t)row * Ntot + col] = (OutT)f2bf(val);
                    else
                        Cout[(size_t)row * Ntot + col] = (OutT)val;
                }
            }
        }
    }
}

// ---------------------------------------------------------------------------
// Sampling: 2 queries per block, 2 channels per thread (uint bf16-pair loads).
// Phase 1 (threads 0..191): per (query q, head m, point j) softmax weight +
// 4 corner indices + premultiplied bilinear weights -> LDS.
// Phase 2: thread = (q = t>>7, head = (t&127)>>4, chanpair = t&15).
// ---------------------------------------------------------------------------
__global__ __launch_bounds__(256) void sample_kernel(
    const float* __restrict__ S,       // [B*NQ, 288]
    const float* __restrict__ refp,    // [B*NQ, 2]
    const u16* __restrict__ proj,      // [B, P_, 256] bf16
    u16* __restrict__ out2)            // [B*NQ, 256] bf16
{
    constexpr int Wd[3]   = {100, 50, 25};
    constexpr int offs[3] = {0, 10000, 12500};

    __shared__ int   midx[192][4];
    __shared__ float mw[192][4];

    const int t = threadIdx.x;

    if (t < 192) {
        const int q  = t / 96;
        const int tq = t % 96;
        const int tm = tq / 12;      // head
        const int tj = tq % 12;      // point = l*4+k
        const int bq = blockIdx.x * 2 + q;
        const float* Sq = S + (size_t)bq * 288;

        float lg[12], mx = -1e30f;
        #pragma unroll
        for (int jj = 0; jj < 12; ++jj) {
            lg[jj] = Sq[192 + tm * 12 + jj];
            mx = fmaxf(mx, lg[jj]);
        }
        float sum = 0.f;
        #pragma unroll
        for (int jj = 0; jj < 12; ++jj) sum += __expf(lg[jj] - mx);
        const float attn = __expf(lg[tj] - mx) / sum;

        const int l  = tj >> 2;
        const int Wl = Wd[l];
        const float refx = refp[(size_t)bq * 2 + 0];
        const float refy = refp[(size_t)bq * 2 + 1];
        const float ox = Sq[(tm * 12 + tj) * 2 + 0];
        const float oy = Sq[(tm * 12 + tj) * 2 + 1];
        const float px = refx * (float)Wl + ox - 0.5f;   // H==W per level
        const float py = refy * (float)Wl + oy - 0.5f;
        const float x0f = floorf(px), y0f = floorf(py);
        const float wx1 = px - x0f, wy1 = py - y0f;
        const float wx0 = 1.f - wx1, wy0 = 1.f - wy1;
        const int x0 = (int)x0f, y0 = (int)y0f;
        const int x1 = x0 + 1, y1 = y0 + 1;
        const bool vx0 = (unsigned)x0 < (unsigned)Wl;
        const bool vx1 = (unsigned)x1 < (unsigned)Wl;
        const bool vy0 = (unsigned)y0 < (unsigned)Wl;
        const bool vy1 = (unsigned)y1 < (unsigned)Wl;
        const int chb  = tm * 32;
        const int base = offs[l];
        midx[t][0] = (vx0 && vy0) ? ((base + y0 * Wl + x0) * 256 + chb) : 0;
        midx[t][1] = (vx1 && vy0) ? ((base + y0 * Wl + x1) * 256 + chb) : 0;
        midx[t][2] = (vx0 && vy1) ? ((base + y1 * Wl + x0) * 256 + chb) : 0;
        midx[t][3] = (vx1 && vy1) ? ((base + y1 * Wl + x1) * 256 + chb) : 0;
        mw[t][0] = (vx0 && vy0) ? attn * wx0 * wy0 : 0.f;
        mw[t][1] = (vx1 && vy0) ? attn * wx1 * wy0 : 0.f;
        mw[t][2] = (vx0 && vy1) ? attn * wx0 * wy1 : 0.f;
        mw[t][3] = (vx1 && vy1) ? attn * wx1 * wy1 : 0.f;
    }
    __syncthreads();

    const int qi  = t >> 7;
    const int tt  = t & 127;
    const int mh  = tt >> 4;
    const int d16 = tt & 15;
    const int bq2 = blockIdx.x * 2 + qi;
    const int b   = bq2 / NQ_;
    const u16* projb = proj + (size_t)b * P_ * 256 + 2 * d16;

    float acc0 = 0.f, acc1 = 0.f;

    #pragma unroll
    for (int j = 0; j < 12; ++j) {
        const int mj = qi * 96 + mh * 12 + j;
        const int4   o  = *reinterpret_cast<const int4*>(midx[mj]);
        const float4 ww = *reinterpret_cast<const float4*>(mw[mj]);
        const unsigned u00 = *reinterpret_cast<const unsigned*>(projb + o.x);
        const unsigned u10 = *reinterpret_cast<const unsigned*>(projb + o.y);
        const unsigned u01 = *reinterpret_cast<const unsigned*>(projb + o.z);
        const unsigned u11 = *reinterpret_cast<const unsigned*>(projb + o.w);
        union { unsigned u; float f; } c0, c1;
        c0.u = u00 << 16;          c1.u = u00 & 0xffff0000u;
        acc0 = fmaf(ww.x, c0.f, acc0); acc1 = fmaf(ww.x, c1.f, acc1);
        c0.u = u10 << 16;          c1.u = u10 & 0xffff0000u;
        acc0 = fmaf(ww.y, c0.f, acc0); acc1 = fmaf(ww.y, c1.f, acc1);
        c0.u = u01 << 16;          c1.u = u01 & 0xffff0000u;
        acc0 = fmaf(ww.z, c0.f, acc0); acc1 = fmaf(ww.z, c1.f, acc1);
        c0.u = u11 << 16;          c1.u = u11 & 0xffff0000u;
        acc0 = fmaf(ww.w, c0.f, acc0); acc1 = fmaf(ww.w, c1.f, acc1);
    }

    const unsigned packed = (unsigned)f2bf(acc0) | ((unsigned)f2bf(acc1) << 16);
    *reinterpret_cast<unsigned*>(out2 + (size_t)bq2 * 256 + mh * 32 + 2 * d16) = packed;
}

// ---------------------------------------------------------------------------
extern "C" void kernel_launch(void* const* d_in, const int* in_sizes, int n_in,
                              void* d_out, int out_size, void* d_ws, size_t ws_size,
                              hipStream_t stream)
{
    const float* query = (const float*)d_in[0];
    const float* refp  = (const float*)d_in[1];
    const float* v0    = (const float*)d_in[2];
    const float* v1    = (const float*)d_in[3];
    const float* v2    = (const float*)d_in[4];
    const float* Wv    = (const float*)d_in[5];
    const float* bv    = (const float*)d_in[6];
    const float* Ws    = (const float*)d_in[7];
    const float* bs    = (const float*)d_in[8];
    const float* Wa    = (const float*)d_in[9];
    const float* ba    = (const float*)d_in[10];
    const float* Wo    = (const float*)d_in[11];
    const float* bo    = (const float*)d_in[12];
    float* out = (float*)d_out;

    char* wsb = (char*)d_ws;
    u16*   proj  = (u16*)wsb;    wsb += (size_t)B_ * P_ * 256 * 2;   // 13.44 MB
    float* S     = (float*)wsb;  wsb += (size_t)B_ * NQ_ * 288 * 4;  // 23.04 MB
    u16*   Vt    = (u16*)wsb;    wsb += (size_t)B_ * P_ * 256 * 2;   // 13.44 MB
    u16*   out2  = (u16*)wsb;    wsb += (size_t)B_ * NQ_ * 256 * 2;  // 10.24 MB

    dim3 blk(256);

    // 0) value transpose+cvt -> Vt bf16 [b][pixel][c]
    transpose_value<<<dim3(157, 4, 6), blk, 0, stream>>>(v0, v1, v2, Vt);

    // 1) value projection -> proj bf16.  nRowTiles=206, npanel=4 -> 26*4*8
    gemm_panel<false, u16><<<dim3(832), blk, 0, stream>>>(
        Vt, B_ * P_, 206, 4, Wv, bv, 256, Wv, bv, 256, proj);

    // 2) offsets+logits -> S f32.  nRowTiles=157, npanel=5 -> 20*5*8
    gemm_panel<true, float><<<dim3(800), blk, 0, stream>>>(
        query, B_ * NQ_, 157, 5, Ws, bs, 192, Wa, ba, 288, S);

    // 3) softmax + bilinear sampling -> out2 bf16 (2 queries / block)
    sample_kernel<<<dim3(NQ_), blk, 0, stream>>>(S, refp, proj, out2);

    // 4) output projection -> d_out f32.  nRowTiles=157, npanel=4 -> 20*4*8
    gemm_panel<false, float><<<dim3(640), blk, 0, stream>>>(
        out2, B_ * NQ_, 157, 4, Wo, bo, 256, Wo, bo, 256, out);
}